// Round 16
// baseline (355.184 us; speedup 1.0000x reference)
//
#include <hip/hip_runtime.h>
#include <math.h>

#define NN 100000
#define EE 3200000
#define ET (EE + NN)
#define NG 64

// bucket sort params
#define NB 196         // ceil(NN/512) buckets
#define BWID 512       // nodes per bucket (dst >> 9)
#define PCHUNK 4096    // edges per partition block (small -> 23KB LDS -> 6 blocks/CU)
#define PBLOCKS ((ET + PCHUNK - 1) / PCHUNK)
#define PART_SMEM (NB * 12 + 1024 + PCHUNK * 4 + PCHUNK)   // cnt/lbase/gbase + sc + buf + bkt

// xform1 split (merged-kernel halves), 128 nodes per 512-thread block
#define X1_SPLIT 50048
#define X1BLK_A 391    // ceil(50048/128)
#define X1BLK_B 391    // ceil((NN-X1_SPLIT)/128)

// workspace layout (4-byte units)
#define OFF_XL1B  0u           /* ushort[NN*32] = 1.6M floats */
#define OFF_XR1   1600000u     /* f32 3.2M -> ends 4.8M */
#define OFF_HL2B  8000000u     /* ushort[NN*64] = 3.2M floats -> 11.2M */
#define OFF_HR2   11200000u    /* f32 6.4M -> 17.6M */
#define OFF_BEDGE 8000000u     /* packed int[ET] = 3.3M, aliases HL2B head (dead before gather1x2) */
#define OFF_RP    17600000u    /* 100096 */
#define OFF_ESRC  17700096u    /* ET = 3.3M -> 21000096 */
#define OFF_POOL  21000096u    /* 4096 */
#define OFF_CNTG  21004192u    /* 64 */
#define OFF_BCNT  21004256u    /* 256 */
#define OFF_BOFF  21004512u    /* 256 */
#define OFF_GCUR  21004768u    /* 256 */
#define OFF_AL2   21005024u    /* f32[NN] */
#define OFF_AR2   21105024u    /* f32[NN] */
#define WS_UNITS  21205024u

__device__ __forceinline__ float lrelu(float v) { return fmaxf(v, 0.2f * v); }

__device__ __forceinline__ unsigned pack_bf2(float a, float b) {
  unsigned ua = __float_as_uint(a), ub = __float_as_uint(b);
  ua = (ua + 0x7FFFu + ((ua >> 16) & 1u)) >> 16;
  ub = (ub + 0x7FFFu + ((ub >> 16) & 1u)) & 0xFFFF0000u;
  return ua | ub;
}
__device__ __forceinline__ float bf_lo(unsigned u) { return __uint_as_float(u << 16); }
__device__ __forceinline__ float bf_hi(unsigned u) { return __uint_as_float(u & 0xFFFF0000u); }

// ---- packed fp32 (2 FLOP/issue) ----
typedef float f32x2 __attribute__((ext_vector_type(2)));
__device__ __forceinline__ f32x2 pk_add(f32x2 a, f32x2 b) {
  f32x2 r; asm("v_pk_add_f32 %0, %1, %2" : "=v"(r) : "v"(a), "v"(b)); return r;
}
__device__ __forceinline__ f32x2 pk_mul(f32x2 a, f32x2 b) {
  f32x2 r; asm("v_pk_mul_f32 %0, %1, %2" : "=v"(r) : "v"(a), "v"(b)); return r;
}
__device__ __forceinline__ f32x2 pk_fma(f32x2 a, f32x2 b, f32x2 c) {
  f32x2 r; asm("v_pk_fma_f32 %0, %1, %2, %3" : "=v"(r) : "v"(a), "v"(b), "v"(c)); return r;
}
__device__ __forceinline__ f32x2 unpk2(unsigned u) {
  f32x2 r; r.x = __uint_as_float(u << 16); r.y = __uint_as_float(u & 0xFFFF0000u); return r;
}
__device__ __forceinline__ f32x2 abs2(f32x2 a) {
  f32x2 r;
  r.x = __uint_as_float(__float_as_uint(a.x) & 0x7FFFFFFFu);
  r.y = __uint_as_float(__float_as_uint(a.y) & 0x7FFFFFFFu);
  return r;
}

// ======================= small CSR kernels =======================
__global__ __launch_bounds__(256) void k_bcount(const int* __restrict__ ei,
                                                int* __restrict__ bcnt) {
  __shared__ int h[NB];
  for (int i = threadIdx.x; i < NB; i += 256) h[i] = 0;
  __syncthreads();
  for (long e = (long)blockIdx.x * 256 + threadIdx.x; e < ET; e += (long)gridDim.x * 256) {
    int d = (e < EE) ? ei[EE + e] : (int)(e - EE);
    atomicAdd(&h[d >> 9], 1);
  }
  __syncthreads();
  for (int i = threadIdx.x; i < NB; i += 256) if (h[i]) atomicAdd(&bcnt[i], h[i]);
}

__global__ __launch_bounds__(256) void k_bscan(const int* __restrict__ bcnt,
                                               int* __restrict__ boff, int* __restrict__ gcur) {
  __shared__ int sd[256];
  int t = threadIdx.x;
  int v = (t < NB) ? bcnt[t] : 0;
  sd[t] = v;
  __syncthreads();
  for (int o = 1; o < 256; o <<= 1) {
    int u = (t >= o) ? sd[t - o] : 0;
    __syncthreads();
    sd[t] += u;
    __syncthreads();
  }
  if (t < NB) { boff[t] = sd[t] - v; gcur[t] = sd[t] - v; }
  if (t == 0) boff[NB] = ET;
}

// ======================= device roles for merged kernels =======================
__device__ void part_role(char* smem, const int* __restrict__ ei,
                          int* __restrict__ gcur, int* __restrict__ bedge, int pblk) {
  int* cnt   = (int*)smem;
  int* lbase = cnt + NB;
  int* gbase = lbase + NB;
  int* sc    = gbase + NB;
  int* buf   = sc + 256;
  unsigned char* bkt = (unsigned char*)(buf + PCHUNK);
  int tid = threadIdx.x;
  long e0 = (long)pblk * PCHUNK;
  int nedge = (e0 + PCHUNK <= ET) ? PCHUNK : (int)(ET - e0);

  for (int i = tid; i < NB; i += 512) cnt[i] = 0;
  __syncthreads();
  for (int i = tid; i < nedge; i += 512) {
    long e = e0 + i;
    int d = (e < EE) ? ei[EE + e] : (int)(e - EE);
    atomicAdd(&cnt[d >> 9], 1);
  }
  __syncthreads();
  if (tid < 256) sc[tid] = (tid < NB) ? cnt[tid] : 0;
  __syncthreads();
  for (int o = 1; o < 256; o <<= 1) {
    int u = (tid < 256 && tid >= o) ? sc[tid - o] : 0;
    __syncthreads();
    if (tid < 256) sc[tid] += u;
    __syncthreads();
  }
  if (tid < NB) lbase[tid] = sc[tid] - cnt[tid];
  __syncthreads();
  if (tid < NB) {
    int c = cnt[tid];
    gbase[tid] = c ? atomicAdd(&gcur[tid], c) : 0;
    cnt[tid] = 0;
  }
  __syncthreads();
  for (int i = tid; i < nedge; i += 512) {
    long e = e0 + i;
    int s, d;
    if (e < EE) { s = ei[e]; d = ei[EE + e]; }
    else { s = (int)(e - EE); d = s; }
    int b = d >> 9;
    int r = atomicAdd(&cnt[b], 1);
    int idx = lbase[b] + r;
    buf[idx] = s | ((d & 511) << 17);
    bkt[idx] = (unsigned char)b;
  }
  __syncthreads();
  for (int i = tid; i < nedge; i += 512) {
    int p = buf[i];
    int b = bkt[i];
    bedge[gbase[b] + (i - lbase[b])] = p;
  }
}

__device__ void csr_role(char* smem, const int* __restrict__ boff,
                         const int* __restrict__ bedge,
                         int* __restrict__ rp, int* __restrict__ esrc, int b) {
  int* sdeg  = (int*)smem;
  int* sscan = sdeg + BWID;
  int t = threadIdx.x;
  int n0 = b * BWID;
  int lo = boff[b], hi = boff[b + 1];
  sdeg[t] = 0;
  __syncthreads();
  for (int i = lo + t; i < hi; i += 512) {
    int p = bedge[i];
    atomicAdd(&sdeg[p >> 17], 1);
  }
  __syncthreads();
  int v = sdeg[t];
  sscan[t] = v;
  __syncthreads();
  for (int o = 1; o < 512; o <<= 1) {
    int u = (t >= o) ? sscan[t - o] : 0;
    __syncthreads();
    sscan[t] += u;
    __syncthreads();
  }
  int excl = sscan[t] - v;
  int n = n0 + t;
  if (n < NN) rp[n] = lo + excl;
  if (b == NB - 1 && t == 0) rp[NN] = ET;
  __syncthreads();
  sdeg[t] = lo + excl;   // reuse as cursor
  __syncthreads();
  for (int i = lo + t; i < hi; i += 512) {
    int p = bedge[i];
    int pos = atomicAdd(&sdeg[p >> 17], 1);
    esrc[pos] = p & 0x1FFFF;
  }
}

// xform1 role (512 threads, 128 nodes/block): 4-node blocking, 16KB W-quarters
#define FMA4A(a, xv) \
  a.x += xv.x*w0.x + xv.y*w1.x + xv.z*w2.x + xv.w*w3.x; \
  a.y += xv.x*w0.y + xv.y*w1.y + xv.z*w2.y + xv.w*w3.y; \
  a.z += xv.x*w0.z + xv.y*w1.z + xv.z*w2.z + xv.w*w3.z; \
  a.w += xv.x*w0.w + xv.y*w1.w + xv.z*w2.w + xv.w*w3.w;

__device__ void xform1_role(char* smem, const float* __restrict__ x,
                            const float* __restrict__ Wl, const float* __restrict__ bl,
                            const float* __restrict__ Wr, const float* __restrict__ br,
                            unsigned short* __restrict__ xl1b, float* __restrict__ xr1,
                            int n_base) {
  float* Wlds = (float*)smem;   // 64*64 floats = 16 KB per quarter
  int tid = threadIdx.x;
  int ci = tid & 15;
  int cbase = ci * 4;
  int n0 = n_base + (tid >> 4) * 4;
  int r0 = n0 + 0 < NN ? n0 + 0 : NN - 1;
  int r1 = n0 + 1 < NN ? n0 + 1 : NN - 1;
  int r2 = n0 + 2 < NN ? n0 + 2 : NN - 1;
  int r3 = n0 + 3 < NN ? n0 + 3 : NN - 1;
  const float* xb0 = x + (size_t)r0 * 256;
  const float* xb1 = x + (size_t)r1 * 256;
  const float* xb2 = x + (size_t)r2 * 256;
  const float* xb3 = x + (size_t)r3 * 256;
  float4 acc0 = {0,0,0,0}, acc1 = {0,0,0,0}, acc2 = {0,0,0,0}, acc3 = {0,0,0,0};

  for (int q = 0; q < 4; ++q) {
    int k0 = q * 64;
    __syncthreads();
    for (int i = tid; i < 64 * 64; i += 512) {
      int k = (i >> 6) + k0, c = i & 63;
      Wlds[i] = (c < 32) ? Wl[k * 32 + c] : Wr[k * 32 + (c - 32)];
    }
    __syncthreads();
#pragma unroll 2
    for (int kk = 0; kk < 64; kk += 4) {
      int k = k0 + kk;
      float4 xv0 = *(const float4*)(xb0 + k);
      float4 xv1 = *(const float4*)(xb1 + k);
      float4 xv2 = *(const float4*)(xb2 + k);
      float4 xv3 = *(const float4*)(xb3 + k);
      const float* wr = &Wlds[kk * 64 + cbase];
      float4 w0 = *(const float4*)(wr);
      float4 w1 = *(const float4*)(wr + 64);
      float4 w2 = *(const float4*)(wr + 128);
      float4 w3 = *(const float4*)(wr + 192);
      FMA4A(acc0, xv0)
      FMA4A(acc1, xv1)
      FMA4A(acc2, xv2)
      FMA4A(acc3, xv3)
    }
  }
  float4 acc[4] = {acc0, acc1, acc2, acc3};
  if (cbase < 32) {
    float4 bv = { bl[cbase], bl[cbase+1], bl[cbase+2], bl[cbase+3] };
#pragma unroll
    for (int j = 0; j < 4; ++j) {
      int n = n0 + j;
      if (n < NN) {
        uint2 o = { pack_bf2(acc[j].x + bv.x, acc[j].y + bv.y),
                    pack_bf2(acc[j].z + bv.z, acc[j].w + bv.w) };
        *(uint2*)(xl1b + (size_t)n * 32 + cbase) = o;
      }
    }
  } else {
    int c2 = cbase - 32;
    float4 bv = { br[c2], br[c2+1], br[c2+2], br[c2+3] };
#pragma unroll
    for (int j = 0; j < 4; ++j) {
      int n = n0 + j;
      if (n < NN) {
        float4 o = { acc[j].x + bv.x, acc[j].y + bv.y, acc[j].z + bv.z, acc[j].w + bv.w };
        *(float4*)(xr1 + (size_t)n * 32 + c2) = o;
      }
    }
  }
}

// ======================= merged kernels (role by blockIdx) =======================
__global__ __launch_bounds__(512) void k_part_x1(
    const int* __restrict__ ei, int* __restrict__ gcur, int* __restrict__ bedge,
    const float* __restrict__ x,
    const float* __restrict__ Wl, const float* __restrict__ bl,
    const float* __restrict__ Wr, const float* __restrict__ br,
    unsigned short* __restrict__ xl1b, float* __restrict__ xr1) {
  extern __shared__ char smem[];
  if (blockIdx.x < PBLOCKS)
    part_role(smem, ei, gcur, bedge, blockIdx.x);
  else
    xform1_role(smem, x, Wl, bl, Wr, br, xl1b, xr1, (blockIdx.x - PBLOCKS) * 128);
}

__global__ __launch_bounds__(512) void k_csr_x1(
    const int* __restrict__ boff, const int* __restrict__ bedge,
    int* __restrict__ rp, int* __restrict__ esrc,
    const float* __restrict__ x,
    const float* __restrict__ Wl, const float* __restrict__ bl,
    const float* __restrict__ Wr, const float* __restrict__ br,
    unsigned short* __restrict__ xl1b, float* __restrict__ xr1) {
  extern __shared__ char smem[];
  if (blockIdx.x < NB)
    csr_role(smem, boff, bedge, rp, esrc, blockIdx.x);
  else
    xform1_role(smem, x, Wl, bl, Wr, br, xl1b, xr1,
                X1_SPLIT + (blockIdx.x - NB) * 128);
}

// ======================= fused layer-1 gather + layer-2 transform + att-dot =====
__global__ __launch_bounds__(256) void k_gather1x2(
    const int* __restrict__ rp, const int* __restrict__ esrc,
    const unsigned short* __restrict__ xl1b, const float* __restrict__ xr1,
    const float* __restrict__ att1, const float* __restrict__ bias1,
    const float* __restrict__ W2l, const float* __restrict__ b2l,
    const float* __restrict__ W2r, const float* __restrict__ b2r,
    const float* __restrict__ att2,
    unsigned short* __restrict__ hl2b, float* __restrict__ hr2,
    float* __restrict__ AL2, float* __restrict__ AR2) {
  __shared__ float W2lds[32 * 128];   // 16 KB
  __shared__ float hlds[8][33];       // +1 pad
  int tid = threadIdx.x;
  for (int i = tid; i < 32 * 128; i += 256) {
    int k = i >> 7, c = i & 127;
    W2lds[i] = (c < 64) ? W2l[k * 64 + c] : W2r[k * 64 + (c - 64)];
  }
  int n = blockIdx.x * 8 + (tid >> 5);   // NN % 8 == 0, grid exact
  int l = tid & 31;
  float av = att1[l];
  float xr = xr1[(size_t)n * 32 + l];
  int rpn = rp[n], dg = rp[n + 1] - rpn;
  float acc = 0.0f, den = 0.0f;
  int j = 0;
  for (; j + 4 <= dg; j += 4) {
    int s0 = esrc[rpn + j + 0];
    int s1 = esrc[rpn + j + 1];
    int s2 = esrc[rpn + j + 2];
    int s3 = esrc[rpn + j + 3];
    float x0 = bf_lo(xl1b[(size_t)s0 * 32 + l]);
    float x1 = bf_lo(xl1b[(size_t)s1 * 32 + l]);
    float x2 = bf_lo(xl1b[(size_t)s2 * 32 + l]);
    float x3 = bf_lo(xl1b[(size_t)s3 * 32 + l]);
    float p0 = lrelu(x0 + xr) * av;
    float p1 = lrelu(x1 + xr) * av;
    float p2 = lrelu(x2 + xr) * av;
    float p3 = lrelu(x3 + xr) * av;
    p0 += __shfl_xor(p0, 1); p1 += __shfl_xor(p1, 1);
    p2 += __shfl_xor(p2, 1); p3 += __shfl_xor(p3, 1);
    p0 += __shfl_xor(p0, 2); p1 += __shfl_xor(p1, 2);
    p2 += __shfl_xor(p2, 2); p3 += __shfl_xor(p3, 2);
    float w0 = __expf(p0), w1 = __expf(p1), w2 = __expf(p2), w3 = __expf(p3);
    den += w0 + w1 + w2 + w3;
    acc += w0 * x0 + w1 * x1 + w2 * x2 + w3 * x3;
  }
  for (; j < dg; ++j) {
    int s = esrc[rpn + j];
    float xl = bf_lo(xl1b[(size_t)s * 32 + l]);
    float p = lrelu(xl + xr) * av;
    p += __shfl_xor(p, 1);
    p += __shfl_xor(p, 2);
    float w = __expf(p);
    den += w;
    acc += w * xl;
  }
  float v = acc / (den + 1e-16f) + bias1[l];
  v = v > 0.0f ? v : expm1f(v);
  hlds[tid >> 5][l] = v;
  __syncthreads();

  // layer-2 transform from LDS
  int ni = tid >> 5, ci = tid & 31, cbase = ci * 4;
  float4 a = {0,0,0,0};
#pragma unroll
  for (int k = 0; k < 32; ++k) {
    float hv = hlds[ni][k];
    float4 wv = *(const float4*)(&W2lds[k * 128 + cbase]);
    a.x += hv * wv.x; a.y += hv * wv.y; a.z += hv * wv.z; a.w += hv * wv.w;
  }
  int no = blockIdx.x * 8 + ni;
  float partial;
  if (cbase < 64) {
    uint2 o = { pack_bf2(a.x + b2l[cbase], a.y + b2l[cbase + 1]),
                pack_bf2(a.z + b2l[cbase + 2], a.w + b2l[cbase + 3]) };
    *(uint2*)(hl2b + (size_t)no * 64 + cbase) = o;
    partial = bf_lo(o.x) * att2[cbase + 0] + bf_hi(o.x) * att2[cbase + 1]
            + bf_lo(o.y) * att2[cbase + 2] + bf_hi(o.y) * att2[cbase + 3];
  } else {
    int c2 = cbase - 64;
    float4 o = { a.x + b2r[c2], a.y + b2r[c2 + 1], a.z + b2r[c2 + 2], a.w + b2r[c2 + 3] };
    *(float4*)(hr2 + (size_t)no * 64 + c2) = o;
    partial = o.x * att2[c2 + 0] + o.y * att2[c2 + 1]
            + o.z * att2[c2 + 2] + o.w * att2[c2 + 3];
  }
  partial += __shfl_xor(partial, 1);
  partial += __shfl_xor(partial, 2);
  partial += __shfl_xor(partial, 4);
  partial += __shfl_xor(partial, 8);
  if (ci == 0)  AL2[no] = partial;
  if (ci == 16) AR2[no] = partial;
}

// ======================= layer-2 gather + pooling, unroll x4, pk-f32 =========
// p = 0.6*(AL2[s]+AR2[d]) + 0.4*sum att*|hl+hr|   (lrelu(v)=0.6v+0.4|v|)
#define G2E(qq, u0O, u1O, u2O, u3O, pO) \
  f32x2 u0O = unpk2(qq.x), u1O = unpk2(qq.y), u2O = unpk2(qq.z), u3O = unpk2(qq.w); \
  float pO; { \
    f32x2 pa__ = pk_mul(abs2(pk_add(u0O, hp0)), ap0); \
    pa__ = pk_fma(abs2(pk_add(u1O, hp1)), ap1, pa__); \
    pa__ = pk_fma(abs2(pk_add(u2O, hp2)), ap2, pa__); \
    pa__ = pk_fma(abs2(pk_add(u3O, hp3)), ap3, pa__); \
    pO = pa__.x + pa__.y; }

#define G2A(u0O, u1O, u2O, u3O, ww) { \
  f32x2 wv__; wv__.x = (ww); wv__.y = (ww); \
  A0 = pk_fma(u0O, wv__, A0); A1 = pk_fma(u1O, wv__, A1); \
  A2 = pk_fma(u2O, wv__, A2); A3 = pk_fma(u3O, wv__, A3); }

__global__ __launch_bounds__(256) void k_gather2(
    const int* __restrict__ rp, const int* __restrict__ esrc,
    const unsigned short* __restrict__ hl2b, const float* __restrict__ hr2,
    const float* __restrict__ att2, const float* __restrict__ bias2,
    const int* __restrict__ batch,
    const float* __restrict__ AL2, const float* __restrict__ AR2,
    float* __restrict__ pool, float* __restrict__ cntg) {
  __shared__ float ssum[4][64];
  __shared__ float scnt[4];
  int tid = threadIdx.x;
  int n = (blockIdx.x * 256 + tid) >> 3;
  int l8 = tid & 7;
  int nblk0 = blockIdx.x * 32;
  int gmin = batch[nblk0];
  int gspan = batch[nblk0 + 31] - gmin + 1;   // <=4 (min graph size >> 32)
  ssum[tid >> 6][tid & 63] = 0.0f;
  if (tid < 4) scnt[tid] = 0.0f;
  __syncthreads();

  float4 ac0 = *(const float4*)(att2 + l8 * 8);
  float4 ac1 = *(const float4*)(att2 + l8 * 8 + 4);
  float4 bs0 = *(const float4*)(bias2 + l8 * 8);
  float4 bs1 = *(const float4*)(bias2 + l8 * 8 + 4);
  f32x2 ap0, ap1, ap2, ap3;
  ap0.x = ac0.x; ap0.y = ac0.y; ap1.x = ac0.z; ap1.y = ac0.w;
  ap2.x = ac1.x; ap2.y = ac1.y; ap3.x = ac1.z; ap3.y = ac1.w;
  const float4* hrp = (const float4*)(hr2 + (size_t)n * 64 + l8 * 8);
  float4 h0 = hrp[0], h1 = hrp[1];
  f32x2 hp0, hp1, hp2, hp3;
  hp0.x = h0.x; hp0.y = h0.y; hp1.x = h0.z; hp1.y = h0.w;
  hp2.x = h1.x; hp2.y = h1.y; hp3.x = h1.z; hp3.y = h1.w;
  float ard = 0.6f * AR2[n];
  int rpn = rp[n], dg = rp[n + 1] - rpn;
  f32x2 A0 = {0.f,0.f}, A1 = {0.f,0.f}, A2 = {0.f,0.f}, A3 = {0.f,0.f};
  float den = 0.0f;
  int j = 0;
  for (; j + 4 <= dg; j += 4) {
    int s0 = esrc[rpn + j + 0];
    int s1 = esrc[rpn + j + 1];
    int s2 = esrc[rpn + j + 2];
    int s3 = esrc[rpn + j + 3];
    uint4 q0 = *(const uint4*)(hl2b + (size_t)s0 * 64 + l8 * 8);
    uint4 q1 = *(const uint4*)(hl2b + (size_t)s1 * 64 + l8 * 8);
    uint4 q2 = *(const uint4*)(hl2b + (size_t)s2 * 64 + l8 * 8);
    uint4 q3 = *(const uint4*)(hl2b + (size_t)s3 * 64 + l8 * 8);
    float al0 = AL2[s0], al1 = AL2[s1], al2 = AL2[s2], al3 = AL2[s3];
    G2E(q0, e0u0, e0u1, e0u2, e0u3, p0)
    G2E(q1, e1u0, e1u1, e1u2, e1u3, p1)
    G2E(q2, e2u0, e2u1, e2u2, e2u3, p2)
    G2E(q3, e3u0, e3u1, e3u2, e3u3, p3)
    p0 += __shfl_xor(p0, 1); p1 += __shfl_xor(p1, 1);
    p2 += __shfl_xor(p2, 1); p3 += __shfl_xor(p3, 1);
    p0 += __shfl_xor(p0, 2); p1 += __shfl_xor(p1, 2);
    p2 += __shfl_xor(p2, 2); p3 += __shfl_xor(p3, 2);
    p0 += __shfl_xor(p0, 4); p1 += __shfl_xor(p1, 4);
    p2 += __shfl_xor(p2, 4); p3 += __shfl_xor(p3, 4);
    float w0 = __expf(fmaf(0.6f, al0, fmaf(0.4f, p0, ard)));
    float w1 = __expf(fmaf(0.6f, al1, fmaf(0.4f, p1, ard)));
    float w2 = __expf(fmaf(0.6f, al2, fmaf(0.4f, p2, ard)));
    float w3 = __expf(fmaf(0.6f, al3, fmaf(0.4f, p3, ard)));
    den += w0 + w1 + w2 + w3;
    G2A(e0u0, e0u1, e0u2, e0u3, w0)
    G2A(e1u0, e1u1, e1u2, e1u3, w1)
    G2A(e2u0, e2u1, e2u2, e2u3, w2)
    G2A(e3u0, e3u1, e3u2, e3u3, w3)
  }
  for (; j < dg; ++j) {
    int s = esrc[rpn + j];
    uint4 q0 = *(const uint4*)(hl2b + (size_t)s * 64 + l8 * 8);
    float al = AL2[s];
    G2E(q0, tu0, tu1, tu2, tu3, p)
    p += __shfl_xor(p, 1);
    p += __shfl_xor(p, 2);
    p += __shfl_xor(p, 4);
    float w = __expf(fmaf(0.6f, al, fmaf(0.4f, p, ard)));
    den += w;
    G2A(tu0, tu1, tu2, tu3, w)
  }
  float inv = 1.0f / (den + 1e-16f);
  int gi = batch[n] - gmin;
  float* sp = &ssum[gi][l8 * 8];
  atomicAdd(sp + 0, A0.x * inv + bs0.x);
  atomicAdd(sp + 1, A0.y * inv + bs0.y);
  atomicAdd(sp + 2, A1.x * inv + bs0.z);
  atomicAdd(sp + 3, A1.y * inv + bs0.w);
  atomicAdd(sp + 4, A2.x * inv + bs1.x);
  atomicAdd(sp + 5, A2.y * inv + bs1.y);
  atomicAdd(sp + 6, A3.x * inv + bs1.z);
  atomicAdd(sp + 7, A3.y * inv + bs1.w);
  if (l8 == 0) atomicAdd(&scnt[gi], 1.0f);
  __syncthreads();
  for (int i = tid; i < gspan * 64; i += 256)
    atomicAdd(pool + (size_t)(gmin + (i >> 6)) * 64 + (i & 63), ssum[i >> 6][i & 63]);
  if (tid < gspan) atomicAdd(cntg + gmin + tid, scnt[tid]);
}

__global__ __launch_bounds__(256) void k_final(
    const float* __restrict__ pool, const float* __restrict__ cntg,
    float* __restrict__ out) {
  int i = blockIdx.x * 256 + threadIdx.x;
  if (i < NG * 64) out[i] = pool[i] / fmaxf(cntg[i >> 6], 1.0f);
}

extern "C" void kernel_launch(void* const* d_in, const int* in_sizes, int n_in,
                              void* d_out, int out_size, void* d_ws, size_t ws_size,
                              hipStream_t stream) {
  const float* x     = (const float*)d_in[0];
  const int*   ei    = (const int*)d_in[1];
  const int*   batch = (const int*)d_in[2];
  const float* W1l   = (const float*)d_in[3];
  const float* b1l   = (const float*)d_in[4];
  const float* W1r   = (const float*)d_in[5];
  const float* b1r   = (const float*)d_in[6];
  const float* att1  = (const float*)d_in[7];
  const float* bias1 = (const float*)d_in[8];
  const float* W2l   = (const float*)d_in[9];
  const float* b2l   = (const float*)d_in[10];
  const float* W2r   = (const float*)d_in[11];
  const float* b2r   = (const float*)d_in[12];
  const float* att2  = (const float*)d_in[13];
  const float* bias2 = (const float*)d_in[14];
  float* ws = (float*)d_ws;
  int*   wi = (int*)d_ws;
  float* out = (float*)d_out;

  // zero pool + cntg + bcnt/boff/gcur (contiguous region)
  hipMemsetAsync(ws + OFF_POOL, 0, (size_t)(OFF_AL2 - OFF_POOL) * 4, stream);

  // CSR build; xform1 halves ride along in the part/csr launches (independent work)
  k_bcount<<<512, 256, 0, stream>>>(ei, wi + OFF_BCNT);
  k_bscan<<<1, 256, 0, stream>>>(wi + OFF_BCNT, wi + OFF_BOFF, wi + OFF_GCUR);
  k_part_x1<<<PBLOCKS + X1BLK_A, 512, PART_SMEM, stream>>>(
      ei, wi + OFF_GCUR, wi + OFF_BEDGE,
      x, W1l, b1l, W1r, b1r, (unsigned short*)(ws + OFF_XL1B), ws + OFF_XR1);
  k_csr_x1<<<NB + X1BLK_B, 512, 16384, stream>>>(
      wi + OFF_BOFF, wi + OFF_BEDGE, wi + OFF_RP, wi + OFF_ESRC,
      x, W1l, b1l, W1r, b1r, (unsigned short*)(ws + OFF_XL1B), ws + OFF_XR1);

  // fused layer-1 gather + layer-2 transform + att-dot precompute
  k_gather1x2<<<NN / 8, 256, 0, stream>>>(wi + OFF_RP, wi + OFF_ESRC,
                                          (const unsigned short*)(ws + OFF_XL1B), ws + OFF_XR1,
                                          att1, bias1, W2l, b2l, W2r, b2r, att2,
                                          (unsigned short*)(ws + OFF_HL2B), ws + OFF_HR2,
                                          ws + OFF_AL2, ws + OFF_AR2);
  k_gather2<<<(NN * 8 + 255) / 256, 256, 0, stream>>>(wi + OFF_RP, wi + OFF_ESRC,
                                                      (const unsigned short*)(ws + OFF_HL2B),
                                                      ws + OFF_HR2, att2, bias2, batch,
                                                      ws + OFF_AL2, ws + OFF_AR2,
                                                      ws + OFF_POOL, ws + OFF_CNTG);
  k_final<<<16, 256, 0, stream>>>(ws + OFF_POOL, ws + OFF_CNTG, out);
}

// Round 17
// 328.519 us; speedup vs baseline: 1.0812x; 1.0812x over previous
//
#include <hip/hip_runtime.h>
#include <math.h>

#define NN 100000
#define EE 3200000
#define ET (EE + NN)
#define NG 64

// bucket sort params
#define NB 196         // ceil(NN/512) buckets
#define BWID 512       // nodes per bucket (dst >> 9)
#define PCHUNK 4096    // edges per partition block
#define PBLOCKS ((ET + PCHUNK - 1) / PCHUNK)
#define PART_SMEM (NB * 12 + 1024 + PCHUNK * 4 + PCHUNK)

// xform1 split (merged-kernel halves), 128 nodes per 512-thread block
#define X1_SPLIT 50048
#define X1BLK_A 391
#define X1BLK_B 391

// workspace layout (4-byte units)
#define OFF_XL1B  0u           /* ushort[NN*32] = 1.6M floats */
#define OFF_XR1   1600000u     /* f32 3.2M -> ends 4.8M */
#define OFF_HL2B  8000000u     /* ushort[NN*64] = 3.2M floats -> 11.2M */
#define OFF_HR2   11200000u    /* f32 6.4M -> 17.6M */
#define OFF_BEDGE 8000000u     /* packed int[ET], aliases HL2B head (dead before gather1x2) */
#define OFF_RP    17600000u    /* 100096 */
#define OFF_ESRC  17700096u    /* ET -> 21000096 */
#define OFF_POOL  21000096u    /* 4096 */
#define OFF_CNTG  21004192u    /* 64 */
#define OFF_BCNT  21004256u
#define OFF_BOFF  21004512u
#define OFF_GCUR  21004768u
#define OFF_AL2   21005024u    /* f32[NN] */
#define OFF_AR2   21105024u    /* f32[NN] */
#define WS_UNITS  21205024u

__device__ __forceinline__ float lrelu(float v) { return fmaxf(v, 0.2f * v); }

__device__ __forceinline__ unsigned pack_bf2(float a, float b) {
  unsigned ua = __float_as_uint(a), ub = __float_as_uint(b);
  ua = (ua + 0x7FFFu + ((ua >> 16) & 1u)) >> 16;
  ub = (ub + 0x7FFFu + ((ub >> 16) & 1u)) & 0xFFFF0000u;
  return ua | ub;
}
__device__ __forceinline__ float bf_lo(unsigned u) { return __uint_as_float(u << 16); }
__device__ __forceinline__ float bf_hi(unsigned u) { return __uint_as_float(u & 0xFFFF0000u); }

// ---- packed fp32 (2 FLOP/issue) ----
typedef float f32x2 __attribute__((ext_vector_type(2)));
__device__ __forceinline__ f32x2 pk_add(f32x2 a, f32x2 b) {
  f32x2 r; asm("v_pk_add_f32 %0, %1, %2" : "=v"(r) : "v"(a), "v"(b)); return r;
}
__device__ __forceinline__ f32x2 pk_mul(f32x2 a, f32x2 b) {
  f32x2 r; asm("v_pk_mul_f32 %0, %1, %2" : "=v"(r) : "v"(a), "v"(b)); return r;
}
__device__ __forceinline__ f32x2 pk_fma(f32x2 a, f32x2 b, f32x2 c) {
  f32x2 r; asm("v_pk_fma_f32 %0, %1, %2, %3" : "=v"(r) : "v"(a), "v"(b), "v"(c)); return r;
}
__device__ __forceinline__ f32x2 unpk2(unsigned u) {
  f32x2 r; r.x = __uint_as_float(u << 16); r.y = __uint_as_float(u & 0xFFFF0000u); return r;
}
__device__ __forceinline__ f32x2 abs2(f32x2 a) {
  f32x2 r;
  r.x = __uint_as_float(__float_as_uint(a.x) & 0x7FFFFFFFu);
  r.y = __uint_as_float(__float_as_uint(a.y) & 0x7FFFFFFFu);
  return r;
}

// ======================= small CSR kernels =======================
__global__ __launch_bounds__(256) void k_bcount(const int* __restrict__ ei,
                                                int* __restrict__ bcnt) {
  __shared__ int h[NB];
  for (int i = threadIdx.x; i < NB; i += 256) h[i] = 0;
  __syncthreads();
  for (long e = (long)blockIdx.x * 256 + threadIdx.x; e < ET; e += (long)gridDim.x * 256) {
    int d = (e < EE) ? ei[EE + e] : (int)(e - EE);
    atomicAdd(&h[d >> 9], 1);
  }
  __syncthreads();
  for (int i = threadIdx.x; i < NB; i += 256) if (h[i]) atomicAdd(&bcnt[i], h[i]);
}

__global__ __launch_bounds__(256) void k_bscan(const int* __restrict__ bcnt,
                                               int* __restrict__ boff, int* __restrict__ gcur) {
  __shared__ int sd[256];
  int t = threadIdx.x;
  int v = (t < NB) ? bcnt[t] : 0;
  sd[t] = v;
  __syncthreads();
  for (int o = 1; o < 256; o <<= 1) {
    int u = (t >= o) ? sd[t - o] : 0;
    __syncthreads();
    sd[t] += u;
    __syncthreads();
  }
  if (t < NB) { boff[t] = sd[t] - v; gcur[t] = sd[t] - v; }
  if (t == 0) boff[NB] = ET;
}

// ======================= device roles for merged kernels =======================
__device__ void part_role(char* smem, const int* __restrict__ ei,
                          int* __restrict__ gcur, int* __restrict__ bedge, int pblk) {
  int* cnt   = (int*)smem;
  int* lbase = cnt + NB;
  int* gbase = lbase + NB;
  int* sc    = gbase + NB;
  int* buf   = sc + 256;
  unsigned char* bkt = (unsigned char*)(buf + PCHUNK);
  int tid = threadIdx.x;
  long e0 = (long)pblk * PCHUNK;
  int nedge = (e0 + PCHUNK <= ET) ? PCHUNK : (int)(ET - e0);

  for (int i = tid; i < NB; i += 512) cnt[i] = 0;
  __syncthreads();
  for (int i = tid; i < nedge; i += 512) {
    long e = e0 + i;
    int d = (e < EE) ? ei[EE + e] : (int)(e - EE);
    atomicAdd(&cnt[d >> 9], 1);
  }
  __syncthreads();
  if (tid < 256) sc[tid] = (tid < NB) ? cnt[tid] : 0;
  __syncthreads();
  for (int o = 1; o < 256; o <<= 1) {
    int u = (tid < 256 && tid >= o) ? sc[tid - o] : 0;
    __syncthreads();
    if (tid < 256) sc[tid] += u;
    __syncthreads();
  }
  if (tid < NB) lbase[tid] = sc[tid] - cnt[tid];
  __syncthreads();
  if (tid < NB) {
    int c = cnt[tid];
    gbase[tid] = c ? atomicAdd(&gcur[tid], c) : 0;
    cnt[tid] = 0;
  }
  __syncthreads();
  for (int i = tid; i < nedge; i += 512) {
    long e = e0 + i;
    int s, d;
    if (e < EE) { s = ei[e]; d = ei[EE + e]; }
    else { s = (int)(e - EE); d = s; }
    int b = d >> 9;
    int r = atomicAdd(&cnt[b], 1);
    int idx = lbase[b] + r;
    buf[idx] = s | ((d & 511) << 17);
    bkt[idx] = (unsigned char)b;
  }
  __syncthreads();
  for (int i = tid; i < nedge; i += 512) {
    int p = buf[i];
    int b = bkt[i];
    bedge[gbase[b] + (i - lbase[b])] = p;
  }
}

__device__ void csr_role(char* smem, const int* __restrict__ boff,
                         const int* __restrict__ bedge,
                         int* __restrict__ rp, int* __restrict__ esrc, int b) {
  int* sdeg  = (int*)smem;
  int* sscan = sdeg + BWID;
  int t = threadIdx.x;
  int n0 = b * BWID;
  int lo = boff[b], hi = boff[b + 1];
  sdeg[t] = 0;
  __syncthreads();
  for (int i = lo + t; i < hi; i += 512) {
    int p = bedge[i];
    atomicAdd(&sdeg[p >> 17], 1);
  }
  __syncthreads();
  int v = sdeg[t];
  sscan[t] = v;
  __syncthreads();
  for (int o = 1; o < 512; o <<= 1) {
    int u = (t >= o) ? sscan[t - o] : 0;
    __syncthreads();
    sscan[t] += u;
    __syncthreads();
  }
  int excl = sscan[t] - v;
  int n = n0 + t;
  if (n < NN) rp[n] = lo + excl;
  if (b == NB - 1 && t == 0) rp[NN] = ET;
  __syncthreads();
  sdeg[t] = lo + excl;   // reuse as cursor
  __syncthreads();
  for (int i = lo + t; i < hi; i += 512) {
    int p = bedge[i];
    int pos = atomicAdd(&sdeg[p >> 17], 1);
    esrc[pos] = p & 0x1FFFF;
  }
}

// xform1 role (512 threads, 128 nodes/block): 4-node blocking, 16KB W-quarters
#define FMA4A(a, xv) \
  a.x += xv.x*w0.x + xv.y*w1.x + xv.z*w2.x + xv.w*w3.x; \
  a.y += xv.x*w0.y + xv.y*w1.y + xv.z*w2.y + xv.w*w3.y; \
  a.z += xv.x*w0.z + xv.y*w1.z + xv.z*w2.z + xv.w*w3.z; \
  a.w += xv.x*w0.w + xv.y*w1.w + xv.z*w2.w + xv.w*w3.w;

__device__ void xform1_role(char* smem, const float* __restrict__ x,
                            const float* __restrict__ Wl, const float* __restrict__ bl,
                            const float* __restrict__ Wr, const float* __restrict__ br,
                            unsigned short* __restrict__ xl1b, float* __restrict__ xr1,
                            int n_base) {
  float* Wlds = (float*)smem;   // 64*64 floats = 16 KB per quarter
  int tid = threadIdx.x;
  int ci = tid & 15;
  int cbase = ci * 4;
  int n0 = n_base + (tid >> 4) * 4;
  int r0 = n0 + 0 < NN ? n0 + 0 : NN - 1;
  int r1 = n0 + 1 < NN ? n0 + 1 : NN - 1;
  int r2 = n0 + 2 < NN ? n0 + 2 : NN - 1;
  int r3 = n0 + 3 < NN ? n0 + 3 : NN - 1;
  const float* xb0 = x + (size_t)r0 * 256;
  const float* xb1 = x + (size_t)r1 * 256;
  const float* xb2 = x + (size_t)r2 * 256;
  const float* xb3 = x + (size_t)r3 * 256;
  float4 acc0 = {0,0,0,0}, acc1 = {0,0,0,0}, acc2 = {0,0,0,0}, acc3 = {0,0,0,0};

  for (int q = 0; q < 4; ++q) {
    int k0 = q * 64;
    __syncthreads();
    for (int i = tid; i < 64 * 64; i += 512) {
      int k = (i >> 6) + k0, c = i & 63;
      Wlds[i] = (c < 32) ? Wl[k * 32 + c] : Wr[k * 32 + (c - 32)];
    }
    __syncthreads();
#pragma unroll 2
    for (int kk = 0; kk < 64; kk += 4) {
      int k = k0 + kk;
      float4 xv0 = *(const float4*)(xb0 + k);
      float4 xv1 = *(const float4*)(xb1 + k);
      float4 xv2 = *(const float4*)(xb2 + k);
      float4 xv3 = *(const float4*)(xb3 + k);
      const float* wr = &Wlds[kk * 64 + cbase];
      float4 w0 = *(const float4*)(wr);
      float4 w1 = *(const float4*)(wr + 64);
      float4 w2 = *(const float4*)(wr + 128);
      float4 w3 = *(const float4*)(wr + 192);
      FMA4A(acc0, xv0)
      FMA4A(acc1, xv1)
      FMA4A(acc2, xv2)
      FMA4A(acc3, xv3)
    }
  }
  float4 acc[4] = {acc0, acc1, acc2, acc3};
  if (cbase < 32) {
    float4 bv = { bl[cbase], bl[cbase+1], bl[cbase+2], bl[cbase+3] };
#pragma unroll
    for (int j = 0; j < 4; ++j) {
      int n = n0 + j;
      if (n < NN) {
        uint2 o = { pack_bf2(acc[j].x + bv.x, acc[j].y + bv.y),
                    pack_bf2(acc[j].z + bv.z, acc[j].w + bv.w) };
        *(uint2*)(xl1b + (size_t)n * 32 + cbase) = o;
      }
    }
  } else {
    int c2 = cbase - 32;
    float4 bv = { br[c2], br[c2+1], br[c2+2], br[c2+3] };
#pragma unroll
    for (int j = 0; j < 4; ++j) {
      int n = n0 + j;
      if (n < NN) {
        float4 o = { acc[j].x + bv.x, acc[j].y + bv.y, acc[j].z + bv.z, acc[j].w + bv.w };
        *(float4*)(xr1 + (size_t)n * 32 + c2) = o;
      }
    }
  }
}

// ======================= merged kernels (role by blockIdx) =======================
__global__ __launch_bounds__(512) void k_part_x1(
    const int* __restrict__ ei, int* __restrict__ gcur, int* __restrict__ bedge,
    const float* __restrict__ x,
    const float* __restrict__ Wl, const float* __restrict__ bl,
    const float* __restrict__ Wr, const float* __restrict__ br,
    unsigned short* __restrict__ xl1b, float* __restrict__ xr1) {
  extern __shared__ char smem[];
  if (blockIdx.x < PBLOCKS)
    part_role(smem, ei, gcur, bedge, blockIdx.x);
  else
    xform1_role(smem, x, Wl, bl, Wr, br, xl1b, xr1, (blockIdx.x - PBLOCKS) * 128);
}

__global__ __launch_bounds__(512) void k_csr_x1(
    const int* __restrict__ boff, const int* __restrict__ bedge,
    int* __restrict__ rp, int* __restrict__ esrc,
    const float* __restrict__ x,
    const float* __restrict__ Wl, const float* __restrict__ bl,
    const float* __restrict__ Wr, const float* __restrict__ br,
    unsigned short* __restrict__ xl1b, float* __restrict__ xr1) {
  extern __shared__ char smem[];
  if (blockIdx.x < NB)
    csr_role(smem, boff, bedge, rp, esrc, blockIdx.x);
  else
    xform1_role(smem, x, Wl, bl, Wr, br, xl1b, xr1,
                X1_SPLIT + (blockIdx.x - NB) * 128);
}

// ======= fused layer-1 gather (8 lanes/node, lane=head, no shuffles) + xform2 =======
// lrelu(v) = 0.6v + 0.4|v|; p_head = sum_c 0.6att*v + 0.4att*|v| entirely in-lane.
// 32 nodes per 256-thread block; xform2+AL/AR epilogue in 4 sub-batches of 8 nodes.
#define G1E(qq, u0O, u1O, pO) \
  f32x2 u0O = unpk2(qq.x), u1O = unpk2(qq.y); \
  float pO; { \
    f32x2 v0__ = pk_add(u0O, xp0), v1__ = pk_add(u1O, xp1); \
    f32x2 d__ = pk_mul(a6p0, v0__); \
    d__ = pk_fma(a6p1, v1__, d__); \
    d__ = pk_fma(a4p0, abs2(v0__), d__); \
    d__ = pk_fma(a4p1, abs2(v1__), d__); \
    pO = d__.x + d__.y; }

__global__ __launch_bounds__(256) void k_gather1x2(
    const int* __restrict__ rp, const int* __restrict__ esrc,
    const unsigned short* __restrict__ xl1b, const float* __restrict__ xr1,
    const float* __restrict__ att1, const float* __restrict__ bias1,
    const float* __restrict__ W2l, const float* __restrict__ b2l,
    const float* __restrict__ W2r, const float* __restrict__ b2r,
    const float* __restrict__ att2,
    unsigned short* __restrict__ hl2b, float* __restrict__ hr2,
    float* __restrict__ AL2, float* __restrict__ AR2) {
  __shared__ float W2lds[32 * 128];   // 16 KB
  __shared__ float hlds[32][33];      // 4.2 KB, +1 pad
  int tid = threadIdx.x;
  for (int i = tid; i < 32 * 128; i += 256) {
    int k = i >> 7, c = i & 127;
    W2lds[i] = (c < 64) ? W2l[k * 64 + c] : W2r[k * 64 + (c - 64)];
  }
  int nl = tid >> 3;                  // local node 0..31
  int n = blockIdx.x * 32 + nl;       // NN % 32 == 0, grid exact
  int l8 = tid & 7;                   // head
  // per-head att pairs, pre-scaled by 0.6 / 0.4
  float4 at = *(const float4*)(att1 + l8 * 4);
  f32x2 a6p0, a6p1, a4p0, a4p1;
  a6p0.x = 0.6f * at.x; a6p0.y = 0.6f * at.y;
  a6p1.x = 0.6f * at.z; a6p1.y = 0.6f * at.w;
  a4p0.x = 0.4f * at.x; a4p0.y = 0.4f * at.y;
  a4p1.x = 0.4f * at.z; a4p1.y = 0.4f * at.w;
  float4 xrv = *(const float4*)(xr1 + (size_t)n * 32 + l8 * 4);
  f32x2 xp0, xp1;
  xp0.x = xrv.x; xp0.y = xrv.y; xp1.x = xrv.z; xp1.y = xrv.w;

  int rpn = rp[n], dg = rp[n + 1] - rpn;
  f32x2 A0 = {0.f,0.f}, A1 = {0.f,0.f};
  float den = 0.0f;
  int j = 0;
  for (; j + 4 <= dg; j += 4) {
    int s0 = esrc[rpn + j + 0];
    int s1 = esrc[rpn + j + 1];
    int s2 = esrc[rpn + j + 2];
    int s3 = esrc[rpn + j + 3];
    uint2 q0 = *(const uint2*)(xl1b + (size_t)s0 * 32 + l8 * 4);
    uint2 q1 = *(const uint2*)(xl1b + (size_t)s1 * 32 + l8 * 4);
    uint2 q2 = *(const uint2*)(xl1b + (size_t)s2 * 32 + l8 * 4);
    uint2 q3 = *(const uint2*)(xl1b + (size_t)s3 * 32 + l8 * 4);
    G1E(q0, e0u0, e0u1, p0)
    G1E(q1, e1u0, e1u1, p1)
    G1E(q2, e2u0, e2u1, p2)
    G1E(q3, e3u0, e3u1, p3)
    float w0 = __expf(p0), w1 = __expf(p1), w2 = __expf(p2), w3 = __expf(p3);
    den += w0 + w1 + w2 + w3;
    f32x2 wv0; wv0.x = w0; wv0.y = w0;
    f32x2 wv1; wv1.x = w1; wv1.y = w1;
    f32x2 wv2; wv2.x = w2; wv2.y = w2;
    f32x2 wv3; wv3.x = w3; wv3.y = w3;
    A0 = pk_fma(e0u0, wv0, A0); A1 = pk_fma(e0u1, wv0, A1);
    A0 = pk_fma(e1u0, wv1, A0); A1 = pk_fma(e1u1, wv1, A1);
    A0 = pk_fma(e2u0, wv2, A0); A1 = pk_fma(e2u1, wv2, A1);
    A0 = pk_fma(e3u0, wv3, A0); A1 = pk_fma(e3u1, wv3, A1);
  }
  for (; j < dg; ++j) {
    int s = esrc[rpn + j];
    uint2 q0 = *(const uint2*)(xl1b + (size_t)s * 32 + l8 * 4);
    G1E(q0, tu0, tu1, p)
    float w = __expf(p);
    den += w;
    f32x2 wv; wv.x = w; wv.y = w;
    A0 = pk_fma(tu0, wv, A0); A1 = pk_fma(tu1, wv, A1);
  }
  float inv = 1.0f / (den + 1e-16f);
  float4 hb = *(const float4*)(bias1 + l8 * 4);
  float h0 = A0.x * inv + hb.x;
  float h1 = A0.y * inv + hb.y;
  float h2 = A1.x * inv + hb.z;
  float h3 = A1.y * inv + hb.w;
  h0 = h0 > 0.0f ? h0 : expm1f(h0);
  h1 = h1 > 0.0f ? h1 : expm1f(h1);
  h2 = h2 > 0.0f ? h2 : expm1f(h2);
  h3 = h3 > 0.0f ? h3 : expm1f(h3);
  hlds[nl][l8 * 4 + 0] = h0;
  hlds[nl][l8 * 4 + 1] = h1;
  hlds[nl][l8 * 4 + 2] = h2;
  hlds[nl][l8 * 4 + 3] = h3;
  __syncthreads();

  // layer-2 transform + att-dot, 4 sub-batches of 8 nodes (old mapping)
  int ni8 = tid >> 5, ci = tid & 31, cbase = ci * 4;
#pragma unroll
  for (int sb = 0; sb < 4; ++sb) {
    int nloc = sb * 8 + ni8;
    float4 a = {0,0,0,0};
#pragma unroll
    for (int k = 0; k < 32; ++k) {
      float hv = hlds[nloc][k];
      float4 wv = *(const float4*)(&W2lds[k * 128 + cbase]);
      a.x += hv * wv.x; a.y += hv * wv.y; a.z += hv * wv.z; a.w += hv * wv.w;
    }
    int no = blockIdx.x * 32 + nloc;
    float partial;
    if (cbase < 64) {
      uint2 o = { pack_bf2(a.x + b2l[cbase], a.y + b2l[cbase + 1]),
                  pack_bf2(a.z + b2l[cbase + 2], a.w + b2l[cbase + 3]) };
      *(uint2*)(hl2b + (size_t)no * 64 + cbase) = o;
      partial = bf_lo(o.x) * att2[cbase + 0] + bf_hi(o.x) * att2[cbase + 1]
              + bf_lo(o.y) * att2[cbase + 2] + bf_hi(o.y) * att2[cbase + 3];
    } else {
      int c2 = cbase - 64;
      float4 o = { a.x + b2r[c2], a.y + b2r[c2 + 1], a.z + b2r[c2 + 2], a.w + b2r[c2 + 3] };
      *(float4*)(hr2 + (size_t)no * 64 + c2) = o;
      partial = o.x * att2[c2 + 0] + o.y * att2[c2 + 1]
              + o.z * att2[c2 + 2] + o.w * att2[c2 + 3];
    }
    partial += __shfl_xor(partial, 1);
    partial += __shfl_xor(partial, 2);
    partial += __shfl_xor(partial, 4);
    partial += __shfl_xor(partial, 8);
    if (ci == 0)  AL2[no] = partial;
    if (ci == 16) AR2[no] = partial;
  }
}

// ======================= layer-2 gather + pooling, unroll x4, pk-f32 =========
#define G2E(qq, u0O, u1O, u2O, u3O, pO) \
  f32x2 u0O = unpk2(qq.x), u1O = unpk2(qq.y), u2O = unpk2(qq.z), u3O = unpk2(qq.w); \
  float pO; { \
    f32x2 pa__ = pk_mul(abs2(pk_add(u0O, hp0)), ap0); \
    pa__ = pk_fma(abs2(pk_add(u1O, hp1)), ap1, pa__); \
    pa__ = pk_fma(abs2(pk_add(u2O, hp2)), ap2, pa__); \
    pa__ = pk_fma(abs2(pk_add(u3O, hp3)), ap3, pa__); \
    pO = pa__.x + pa__.y; }

#define G2A(u0O, u1O, u2O, u3O, ww) { \
  f32x2 wv__; wv__.x = (ww); wv__.y = (ww); \
  A0 = pk_fma(u0O, wv__, A0); A1 = pk_fma(u1O, wv__, A1); \
  A2 = pk_fma(u2O, wv__, A2); A3 = pk_fma(u3O, wv__, A3); }

__global__ __launch_bounds__(256) void k_gather2(
    const int* __restrict__ rp, const int* __restrict__ esrc,
    const unsigned short* __restrict__ hl2b, const float* __restrict__ hr2,
    const float* __restrict__ att2, const float* __restrict__ bias2,
    const int* __restrict__ batch,
    const float* __restrict__ AL2, const float* __restrict__ AR2,
    float* __restrict__ pool, float* __restrict__ cntg) {
  __shared__ float ssum[4][64];
  __shared__ float scnt[4];
  int tid = threadIdx.x;
  int n = (blockIdx.x * 256 + tid) >> 3;
  int l8 = tid & 7;
  int nblk0 = blockIdx.x * 32;
  int gmin = batch[nblk0];
  int gspan = batch[nblk0 + 31] - gmin + 1;   // <=4
  ssum[tid >> 6][tid & 63] = 0.0f;
  if (tid < 4) scnt[tid] = 0.0f;
  __syncthreads();

  float4 ac0 = *(const float4*)(att2 + l8 * 8);
  float4 ac1 = *(const float4*)(att2 + l8 * 8 + 4);
  float4 bs0 = *(const float4*)(bias2 + l8 * 8);
  float4 bs1 = *(const float4*)(bias2 + l8 * 8 + 4);
  f32x2 ap0, ap1, ap2, ap3;
  ap0.x = ac0.x; ap0.y = ac0.y; ap1.x = ac0.z; ap1.y = ac0.w;
  ap2.x = ac1.x; ap2.y = ac1.y; ap3.x = ac1.z; ap3.y = ac1.w;
  const float4* hrp = (const float4*)(hr2 + (size_t)n * 64 + l8 * 8);
  float4 h0 = hrp[0], h1 = hrp[1];
  f32x2 hp0, hp1, hp2, hp3;
  hp0.x = h0.x; hp0.y = h0.y; hp1.x = h0.z; hp1.y = h0.w;
  hp2.x = h1.x; hp2.y = h1.y; hp3.x = h1.z; hp3.y = h1.w;
  float ard = 0.6f * AR2[n];
  int rpn = rp[n], dg = rp[n + 1] - rpn;
  f32x2 A0 = {0.f,0.f}, A1 = {0.f,0.f}, A2 = {0.f,0.f}, A3 = {0.f,0.f};
  float den = 0.0f;
  int j = 0;
  for (; j + 4 <= dg; j += 4) {
    int s0 = esrc[rpn + j + 0];
    int s1 = esrc[rpn + j + 1];
    int s2 = esrc[rpn + j + 2];
    int s3 = esrc[rpn + j + 3];
    uint4 q0 = *(const uint4*)(hl2b + (size_t)s0 * 64 + l8 * 8);
    uint4 q1 = *(const uint4*)(hl2b + (size_t)s1 * 64 + l8 * 8);
    uint4 q2 = *(const uint4*)(hl2b + (size_t)s2 * 64 + l8 * 8);
    uint4 q3 = *(const uint4*)(hl2b + (size_t)s3 * 64 + l8 * 8);
    float al0 = AL2[s0], al1 = AL2[s1], al2 = AL2[s2], al3 = AL2[s3];
    G2E(q0, e0u0, e0u1, e0u2, e0u3, p0)
    G2E(q1, e1u0, e1u1, e1u2, e1u3, p1)
    G2E(q2, e2u0, e2u1, e2u2, e2u3, p2)
    G2E(q3, e3u0, e3u1, e3u2, e3u3, p3)
    p0 += __shfl_xor(p0, 1); p1 += __shfl_xor(p1, 1);
    p2 += __shfl_xor(p2, 1); p3 += __shfl_xor(p3, 1);
    p0 += __shfl_xor(p0, 2); p1 += __shfl_xor(p1, 2);
    p2 += __shfl_xor(p2, 2); p3 += __shfl_xor(p3, 2);
    p0 += __shfl_xor(p0, 4); p1 += __shfl_xor(p1, 4);
    p2 += __shfl_xor(p2, 4); p3 += __shfl_xor(p3, 4);
    float w0 = __expf(fmaf(0.6f, al0, fmaf(0.4f, p0, ard)));
    float w1 = __expf(fmaf(0.6f, al1, fmaf(0.4f, p1, ard)));
    float w2 = __expf(fmaf(0.6f, al2, fmaf(0.4f, p2, ard)));
    float w3 = __expf(fmaf(0.6f, al3, fmaf(0.4f, p3, ard)));
    den += w0 + w1 + w2 + w3;
    G2A(e0u0, e0u1, e0u2, e0u3, w0)
    G2A(e1u0, e1u1, e1u2, e1u3, w1)
    G2A(e2u0, e2u1, e2u2, e2u3, w2)
    G2A(e3u0, e3u1, e3u2, e3u3, w3)
  }
  for (; j < dg; ++j) {
    int s = esrc[rpn + j];
    uint4 q0 = *(const uint4*)(hl2b + (size_t)s * 64 + l8 * 8);
    float al = AL2[s];
    G2E(q0, tu0, tu1, tu2, tu3, p)
    p += __shfl_xor(p, 1);
    p += __shfl_xor(p, 2);
    p += __shfl_xor(p, 4);
    float w = __expf(fmaf(0.6f, al, fmaf(0.4f, p, ard)));
    den += w;
    G2A(tu0, tu1, tu2, tu3, w)
  }
  float inv = 1.0f / (den + 1e-16f);
  int gi = batch[n] - gmin;
  float* sp = &ssum[gi][l8 * 8];
  atomicAdd(sp + 0, A0.x * inv + bs0.x);
  atomicAdd(sp + 1, A0.y * inv + bs0.y);
  atomicAdd(sp + 2, A1.x * inv + bs0.z);
  atomicAdd(sp + 3, A1.y * inv + bs0.w);
  atomicAdd(sp + 4, A2.x * inv + bs1.x);
  atomicAdd(sp + 5, A2.y * inv + bs1.y);
  atomicAdd(sp + 6, A3.x * inv + bs1.z);
  atomicAdd(sp + 7, A3.y * inv + bs1.w);
  if (l8 == 0) atomicAdd(&scnt[gi], 1.0f);
  __syncthreads();
  for (int i = tid; i < gspan * 64; i += 256)
    atomicAdd(pool + (size_t)(gmin + (i >> 6)) * 64 + (i & 63), ssum[i >> 6][i & 63]);
  if (tid < gspan) atomicAdd(cntg + gmin + tid, scnt[tid]);
}

__global__ __launch_bounds__(256) void k_final(
    const float* __restrict__ pool, const float* __restrict__ cntg,
    float* __restrict__ out) {
  int i = blockIdx.x * 256 + threadIdx.x;
  if (i < NG * 64) out[i] = pool[i] / fmaxf(cntg[i >> 6], 1.0f);
}

extern "C" void kernel_launch(void* const* d_in, const int* in_sizes, int n_in,
                              void* d_out, int out_size, void* d_ws, size_t ws_size,
                              hipStream_t stream) {
  const float* x     = (const float*)d_in[0];
  const int*   ei    = (const int*)d_in[1];
  const int*   batch = (const int*)d_in[2];
  const float* W1l   = (const float*)d_in[3];
  const float* b1l   = (const float*)d_in[4];
  const float* W1r   = (const float*)d_in[5];
  const float* b1r   = (const float*)d_in[6];
  const float* att1  = (const float*)d_in[7];
  const float* bias1 = (const float*)d_in[8];
  const float* W2l   = (const float*)d_in[9];
  const float* b2l   = (const float*)d_in[10];
  const float* W2r   = (const float*)d_in[11];
  const float* b2r   = (const float*)d_in[12];
  const float* att2  = (const float*)d_in[13];
  const float* bias2 = (const float*)d_in[14];
  float* ws = (float*)d_ws;
  int*   wi = (int*)d_ws;
  float* out = (float*)d_out;

  hipMemsetAsync(ws + OFF_POOL, 0, (size_t)(OFF_AL2 - OFF_POOL) * 4, stream);

  // CSR build; xform1 halves ride along in the part/csr launches (independent work)
  k_bcount<<<512, 256, 0, stream>>>(ei, wi + OFF_BCNT);
  k_bscan<<<1, 256, 0, stream>>>(wi + OFF_BCNT, wi + OFF_BOFF, wi + OFF_GCUR);
  k_part_x1<<<PBLOCKS + X1BLK_A, 512, PART_SMEM, stream>>>(
      ei, wi + OFF_GCUR, wi + OFF_BEDGE,
      x, W1l, b1l, W1r, b1r, (unsigned short*)(ws + OFF_XL1B), ws + OFF_XR1);
  k_csr_x1<<<NB + X1BLK_B, 512, 16384, stream>>>(
      wi + OFF_BOFF, wi + OFF_BEDGE, wi + OFF_RP, wi + OFF_ESRC,
      x, W1l, b1l, W1r, b1r, (unsigned short*)(ws + OFF_XL1B), ws + OFF_XR1);

  // fused layer-1 gather (8 lanes/node) + layer-2 transform + att-dot precompute
  k_gather1x2<<<NN / 32, 256, 0, stream>>>(wi + OFF_RP, wi + OFF_ESRC,
                                           (const unsigned short*)(ws + OFF_XL1B), ws + OFF_XR1,
                                           att1, bias1, W2l, b2l, W2r, b2r, att2,
                                           (unsigned short*)(ws + OFF_HL2B), ws + OFF_HR2,
                                           ws + OFF_AL2, ws + OFF_AR2);
  k_gather2<<<(NN * 8 + 255) / 256, 256, 0, stream>>>(wi + OFF_RP, wi + OFF_ESRC,
                                                      (const unsigned short*)(ws + OFF_HL2B),
                                                      ws + OFF_HR2, att2, bias2, batch,
                                                      ws + OFF_AL2, ws + OFF_AR2,
                                                      ws + OFF_POOL, ws + OFF_CNTG);
  k_final<<<16, 256, 0, stream>>>(ws + OFF_POOL, ws + OFF_CNTG, out);
}